// Round 8
// baseline (479.801 us; speedup 1.0000x reference)
//
#include <hip/hip_runtime.h>
#include <hip/hip_fp16.h>
#include <math.h>

// Problem constants (fixed by reference)
constexpr int I_N = 40000, U_N = 30000, F_N = 30000;
constexpr int NN   = 100000;           // total nodes
constexpr int EE   = 1200000;          // edges (without self loops)
constexpr int ETOT = EE + NN;          // edges + self loops
constexpr int NBUCK = (NN + 511)/512;  // 196 dst-buckets of 512 nodes

using half8   = __attribute__((ext_vector_type(8))) _Float16;
using h2v     = __attribute__((ext_vector_type(2))) _Float16;
using floatx4 = __attribute__((ext_vector_type(4))) float;

__device__ __forceinline__ float leaky(float x){ return x > 0.f ? x : 0.2f*x; }

// ---------------- binned CSR build (no random global atomics in hot path) ----------------
__global__ __launch_bounds__(256) void zerob_k(int* bsize){
  int i = threadIdx.x;
  if (i < NBUCK) bsize[i] = 0;
}

__global__ __launch_bounds__(256) void hist_k(const int* __restrict__ edst, int* __restrict__ bsize){
  __shared__ int h[NBUCK];
  for (int i = threadIdx.x; i < NBUCK; i += 256) h[i] = 0;
  __syncthreads();
  int stride = gridDim.x*256;
  for (int e = blockIdx.x*256 + threadIdx.x; e < EE; e += stride)
    atomicAdd(&h[edst[e] >> 9], 1);
  __syncthreads();
  for (int i = threadIdx.x; i < NBUCK; i += 256)
    if (h[i]) atomicAdd(&bsize[i], h[i]);
}

__global__ __launch_bounds__(256) void bscan_k(const int* __restrict__ bsize,
                                               int* __restrict__ ebase, int* __restrict__ rbase,
                                               int* __restrict__ gcur, int* __restrict__ row_start){
  __shared__ int sb[NBUCK], se[NBUCK], sr[NBUCK];
  int t = threadIdx.x;
  for (int i = t; i < NBUCK; i += 256) sb[i] = bsize[i];
  __syncthreads();
  if (t == 0){
    int e = 0, r = 0;
    for (int b = 0; b < NBUCK; ++b){
      int nloc = NN - b*512; if (nloc > 512) nloc = 512;
      se[b] = e; sr[b] = r;
      e += sb[b]; r += sb[b] + nloc;
    }
    row_start[NN] = ETOT;
  }
  __syncthreads();
  for (int i = t; i < NBUCK; i += 256){
    ebase[i] = se[i]; gcur[i] = se[i]; rbase[i] = sr[i];
  }
}

__global__ __launch_bounds__(256) void binplace_k(const int* __restrict__ esrc,
                                                  const int* __restrict__ edst,
                                                  int* __restrict__ gcur,
                                                  unsigned long long* __restrict__ binned){
  constexpr int CHUNK = 4096;
  __shared__ int ls[CHUNK], ld[CHUNK];
  __shared__ int h[NBUCK], bb[NBUCK], cur[NBUCK];
  long e0 = (long)blockIdx.x * CHUNK;
  int n = (int)(EE - e0); if (n > CHUNK) n = CHUNK;
  for (int i = threadIdx.x; i < NBUCK; i += 256){ h[i] = 0; cur[i] = 0; }
  __syncthreads();
  for (int i = threadIdx.x; i < n; i += 256){
    int s = esrc[e0+i], d = edst[e0+i];
    ls[i] = s; ld[i] = d;
    atomicAdd(&h[d >> 9], 1);
  }
  __syncthreads();
  for (int b = threadIdx.x; b < NBUCK; b += 256)
    bb[b] = h[b] ? atomicAdd(&gcur[b], h[b]) : 0;
  __syncthreads();
  for (int i = threadIdx.x; i < n; i += 256){
    int d = ld[i], b = d >> 9;
    int p = bb[b] + atomicAdd(&cur[b], 1);
    unsigned long long v = ((unsigned long long)(unsigned)(e0+i) << 32)
                         | (unsigned)(ls[i] | ((d & 511) << 17));
    binned[p] = v;
  }
}

__global__ __launch_bounds__(512) void bbuild_k(const unsigned long long* __restrict__ binned,
                                                const int* __restrict__ bsize,
                                                const int* __restrict__ ebase, const int* __restrict__ rbase,
                                                int* __restrict__ row_start,
                                                int* __restrict__ colsrc, int* __restrict__ eids){
  __shared__ int sm[512], curs[512];
  int b = blockIdx.x, t = threadIdx.x;
  int nbase = b*512;
  int NLOC = NN - nbase; if (NLOC > 512) NLOC = 512;
  int sz = bsize[b], eb = ebase[b], rb = rbase[b];
  sm[t] = (t < NLOC) ? 1 : 0;                  // self loop
  __syncthreads();
  for (int i = t; i < sz; i += 512){
    int lo = (int)(binned[eb+i] & 0xFFFFFFFFu);
    atomicAdd(&sm[(lo >> 17) & 511], 1);
  }
  __syncthreads();
  int myc = sm[t];
  for (int off = 1; off < 512; off <<= 1){
    int x = (t >= off) ? sm[t-off] : 0;
    __syncthreads();
    sm[t] += x;
    __syncthreads();
  }
  int excl = sm[t] - myc;
  if (t < NLOC){
    row_start[nbase+t] = rb + excl;
    colsrc[rb+excl] = nbase + t;               // self loop first in segment
    eids[rb+excl]   = EE + nbase + t;
  }
  curs[t] = excl + ((t < NLOC) ? 1 : 0);
  __syncthreads();
  for (int i = t; i < sz; i += 512){
    unsigned long long v = binned[eb+i];
    int lo  = (int)(v & 0xFFFFFFFFu);
    int dl  = (lo >> 17) & 511;
    int src = lo & 0x1FFFF;
    int p = rb + atomicAdd(&curs[dl], 1);
    colsrc[p] = src;
    eids[p]   = (int)(v >> 32);
  }
}

// ---------------- one-time weight transpose W(KxC) -> WT(CxK) fp16 ----------------
__global__ __launch_bounds__(256) void wtrans_k(const float* __restrict__ W1,
                                                const float* __restrict__ W2,
                                                const float* __restrict__ W3,
                                                __half* __restrict__ wt1,
                                                __half* __restrict__ wt2,
                                                __half* __restrict__ wt3){
  int i = blockIdx.x*256 + threadIdx.x;
  if (i < 64*128){  int k = i >> 7, c = i & 127; wt1[c*64  + k] = __float2half(W1[i]); }
  if (i < 128*128){ int k = i >> 7, c = i & 127; wt2[c*128 + k] = __float2half(W2[i]); }
  if (i < 128*64){  int k = i >> 6, c = i & 63;  wt3[c*128 + k] = __float2half(W3[i]); }
}

// ---------------- MFMA GEMM (+ fused attention dots) — verbatim round 7 ----------------
template<int K, int C, bool CONCAT>
__global__ __launch_bounds__(256) void gemm_mfma_k(
    const float* __restrict__ Xa, const float* __restrict__ Xb, const float* __restrict__ Xc,
    const __half* __restrict__ WT,
    const float* __restrict__ atts, const float* __restrict__ attd,
    __half* __restrict__ XWH, float* __restrict__ asrc, float* __restrict__ adst)
{
  constexpr int RPB = 64;
  constexpr int H   = C/64;
  constexpr int NCT = C/16;
  constexpr size_t STAGE_B = (size_t)(RPB*K + C*K)*2;
  constexpr size_t EPI_B   = (size_t)RPB*(C+4)*4;
  constexpr size_t SMEM_B  = STAGE_B > EPI_B ? STAGE_B : EPI_B;
  __shared__ __align__(16) char smem[SMEM_B];
  _Float16* Xs = (_Float16*)smem;          // [RPB][K]
  _Float16* Bs = Xs + RPB*K;               // [C][K]
  float*    Es = (float*)smem;             // [RPB][C+4] epilogue

  int t = threadIdx.x;
  long rbase = (long)blockIdx.x * RPB;

  for (int i = t; i < RPB*K/4; i += 256){
    float4 v = make_float4(0.f,0.f,0.f,0.f);
    if constexpr (CONCAT){
      long gi = rbase*(K/4) + i;
      if      (gi < (long)I_N*(K/4))        v = ((const float4*)Xa)[gi];
      else if (gi < (long)(I_N+U_N)*(K/4))  v = ((const float4*)Xb)[gi - (long)I_N*(K/4)];
      else if (gi < (long)NN*(K/4))         v = ((const float4*)Xc)[gi - (long)(I_N+U_N)*(K/4)];
    } else {
      if (rbase + i/(K/4) < NN)             v = ((const float4*)(Xa + rbase*K))[i];
    }
    union { __half2 h2[2]; uint2 u; } pk;
    pk.h2[0] = __floats2half2_rn(v.x, v.y);
    pk.h2[1] = __floats2half2_rn(v.z, v.w);
    ((uint2*)Xs)[i] = pk.u;
  }
  for (int i = t; i < C*K/8; i += 256)
    ((uint4*)Bs)[i] = ((const uint4*)WT)[i];
  __syncthreads();

  const int wid = t >> 6, lane = t & 63;
  const int l15 = lane & 15, lk = lane >> 4;
  floatx4 acc[NCT];
  #pragma unroll
  for (int i = 0; i < NCT; ++i) acc[i] = (floatx4){0.f,0.f,0.f,0.f};

  const _Float16* arow = Xs + (wid*16 + l15)*K + lk*8;
  const _Float16* brow = Bs + l15*K + lk*8;
  #pragma unroll
  for (int ks = 0; ks < K/32; ++ks){
    half8 a = *(const half8*)(arow + ks*32);
    #pragma unroll
    for (int ct = 0; ct < NCT; ++ct){
      half8 b = *(const half8*)(brow + ct*16*K + ks*32);
      acc[ct] = __builtin_amdgcn_mfma_f32_16x16x32_f16(a, b, acc[ct], 0, 0, 0);
    }
  }

  float asv[NCT], adv[NCT];
  #pragma unroll
  for (int ct = 0; ct < NCT; ++ct){
    asv[ct] = atts[ct*16 + l15];
    adv[ct] = attd[ct*16 + l15];
  }
  #pragma unroll
  for (int reg = 0; reg < 4; ++reg){
    float p0s = 0.f, p0d = 0.f, p1s = 0.f, p1d = 0.f;
    #pragma unroll
    for (int ct = 0; ct < NCT; ++ct){
      float v = acc[ct][reg];
      if (H == 2 && ct >= NCT/2){ p1s = fmaf(v, asv[ct], p1s); p1d = fmaf(v, adv[ct], p1d); }
      else                      { p0s = fmaf(v, asv[ct], p0s); p0d = fmaf(v, adv[ct], p0d); }
    }
    #pragma unroll
    for (int m = 1; m < 16; m <<= 1){
      p0s += __shfl_xor(p0s, m, 64); p0d += __shfl_xor(p0d, m, 64);
      if (H == 2){ p1s += __shfl_xor(p1s, m, 64); p1d += __shfl_xor(p1d, m, 64); }
    }
    if (l15 == 0){
      long r = rbase + wid*16 + lk*4 + reg;
      if (r < NN){
        asrc[r*H] = p0s; adst[r*H] = p0d;
        if (H == 2){ asrc[r*H+1] = p1s; adst[r*H+1] = p1d; }
      }
    }
  }

  __syncthreads();
  #pragma unroll
  for (int ct = 0; ct < NCT; ++ct)
    #pragma unroll
    for (int reg = 0; reg < 4; ++reg)
      Es[(wid*16 + lk*4 + reg)*(C+4) + ct*16 + l15] = acc[ct][reg];
  __syncthreads();
  for (int i = t; i < RPB*C/4; i += 256){
    int row = i/(C/4), c4 = (i%(C/4))*4;
    if (rbase + row >= NN) continue;
    float4 v = *(const float4*)&Es[row*(C+4) + c4];
    union { __half2 h2[2]; uint2 u; } pk;
    pk.h2[0] = __floats2half2_rn(v.x, v.y);
    pk.h2[1] = __floats2half2_rn(v.z, v.w);
    *(uint2*)&XWH[(rbase+row)*C + c4] = pk.u;
  }
}

// ---------------- aggregation: online softmax + pk_fma_f16 gather + fused alpha/final --
// 1 wave per dst node. Gather operands (byte-offset, fp16-splat q per head) staged in
// wave-private LDS each batch; inner loop = 2 ds_read + saddr load + 4 v_pk_fma_f16.
template<int H, int LAYER>
__global__ __launch_bounds__(256) void aggregate_k(
    const __half* __restrict__ XWH, const float* __restrict__ asrc, const float* __restrict__ adst,
    const int* __restrict__ row_start, const int* __restrict__ colsrc, const int* __restrict__ eids,
    const float* __restrict__ bias, float* __restrict__ aout,
    float* __restrict__ hbuf, float* __restrict__ fin,
    const float* __restrict__ embi, const float* __restrict__ embu, const float* __restrict__ embf,
    float* __restrict__ outp)
{
  constexpr int C = H*64;
  constexpr unsigned ROWB = C*2;               // row bytes (fp16)
  int widx = threadIdx.x >> 6;                 // wave within block
  int wid  = (blockIdx.x*256 + threadIdx.x) >> 6;
  int lane = threadIdx.x & 63;
  __shared__ unsigned ldsOff[4][64];
  __shared__ unsigned ldsQ[4][H][64];
  if (wid >= NN) return;
  int n0 = row_start[wid], n1 = row_start[wid+1];
  int segLen = n1 - n0;

  float ad[H];
  if constexpr (H==2){ float2 t = ((const float2*)adst)[wid]; ad[0]=t.x; ad[1]=t.y; }
  else                 ad[0] = adst[wid];

  constexpr int SL_SH = (H==2) ? 4 : 3;
  const int slot = lane >> SL_SH;
  const int cg   = lane & ((1<<SL_SH)-1);
  const int hd   = (H==2) ? (cg>>3) : 0;
  const char* xwb = (const char*)XWH;
  const unsigned cgoff = (unsigned)cg*16;

  float mx[H], den[H];
  #pragma unroll
  for (int h=0; h<H; ++h){ mx[h] = -3.402823466e38f; den[h] = 0.f; }
  h2v acch[4];
  #pragma unroll
  for (int i=0;i<4;++i) acch[i] = (h2v){(_Float16)0.f, (_Float16)0.f};

  int s = 0, eid = 0;
  float p[H];
  #pragma unroll
  for (int h=0; h<H; ++h) p[h] = 0.f;

  for (int base = n0; base < n1; base += 64){
    int cnt = n1 - base; if (cnt > 64) cnt = 64;
    float e[H];
    #pragma unroll
    for (int h=0; h<H; ++h) e[h] = -3.402823466e38f;
    if (lane < cnt){
      s   = colsrc[base + lane];
      eid = eids[base + lane];
      if constexpr (H==2){
        float2 a = ((const float2*)asrc)[s];
        e[0] = leaky(a.x + ad[0]); e[1] = leaky(a.y + ad[1]);
      } else {
        e[0] = leaky(asrc[s] + ad[0]);
      }
    }
    float sc[H];
    #pragma unroll
    for (int h=0; h<H; ++h){
      float bm = e[h];
      #pragma unroll
      for (int m=1; m<64; m<<=1) bm = fmaxf(bm, __shfl_xor(bm, m, 64));
      float nm = fmaxf(mx[h], bm);
      p[h] = (lane < cnt) ? __expf(e[h] - nm) : 0.f;
      if (base == n0){
        den[h] = p[h]; sc[h] = 1.f;
      } else {
        sc[h] = __expf(mx[h] - nm);
        den[h] = den[h]*sc[h] + p[h];
      }
      mx[h] = nm;
    }
    if (base != n0){
      float asc = (H==2) ? sc[hd] : sc[0];
      h2v av = {(_Float16)asc, (_Float16)asc};
      #pragma unroll
      for (int i=0;i<4;++i) acch[i] *= av;
    }

    // stage gather operands in wave-private LDS
    ldsOff[widx][lane] = (lane < cnt) ? (unsigned)s * ROWB : 0u;
    #pragma unroll
    for (int h=0; h<H; ++h){
      union { __half2 h2; unsigned u; } qq;
      qq.h2 = __floats2half2_rn(p[h], p[h]);
      ldsQ[widx][h][lane] = qq.u;
    }
    __builtin_amdgcn_wave_barrier();

    constexpr int EPI = 64 >> SL_SH;
    for (int j = 0; j < cnt; j += 2*EPI){
      unsigned off[2], qpk[2];
      #pragma unroll
      for (int u=0; u<2; ++u){
        int ei = j + u*EPI + slot;
        off[u] = ldsOff[widx][ei];
        qpk[u] = ldsQ[widx][hd][ei];
      }
      #pragma unroll
      for (int u=0; u<2; ++u){
        float4 raw = *(const float4*)(xwb + (off[u] + cgoff));
        union { float4 f; h2v h[4]; } cv; cv.f = raw;
        union { unsigned u; h2v h; } qv; qv.u = qpk[u];
        #pragma unroll
        for (int i=0;i<4;++i)
          acch[i] = __builtin_elementwise_fma(qv.h, cv.h[i], acch[i]);
      }
    }
    __builtin_amdgcn_wave_barrier();
  }

  float idv[H];
  #pragma unroll
  for (int h=0; h<H; ++h){
    #pragma unroll
    for (int m=1; m<64; m<<=1) den[h] += __shfl_xor(den[h], m, 64);
    idv[h] = 1.0f/(den[h] + 1e-16f);
  }

  float accv[8];
  #pragma unroll
  for (int i=0;i<4;++i){ accv[2*i] = (float)acch[i][0]; accv[2*i+1] = (float)acch[i][1]; }

  // combine edge-slot partial sums: lanes with same cg
  #pragma unroll
  for (int i=0;i<8;++i){
    if constexpr (H==1) accv[i] += __shfl_xor(accv[i], 8, 64);
    accv[i] += __shfl_xor(accv[i], 16, 64);
    accv[i] += __shfl_xor(accv[i], 32, 64);
  }

  float myId = (H==2) ? idv[hd] : idv[0];
  float4 b0 = *(const float4*)&bias[cg*8];
  float4 b1 = *(const float4*)&bias[cg*8 + 4];
  float o[8];
  o[0]=accv[0]*myId+b0.x; o[1]=accv[1]*myId+b0.y; o[2]=accv[2]*myId+b0.z; o[3]=accv[3]*myId+b0.w;
  o[4]=accv[4]*myId+b1.x; o[5]=accv[5]*myId+b1.y; o[6]=accv[6]*myId+b1.z; o[7]=accv[7]*myId+b1.w;

  if constexpr (LAYER==1 || LAYER==2){
    if (lane < 16){
      float4 r0 = make_float4(fmaxf(o[0],0.f), fmaxf(o[1],0.f), fmaxf(o[2],0.f), fmaxf(o[3],0.f));
      float4 r1 = make_float4(fmaxf(o[4],0.f), fmaxf(o[5],0.f), fmaxf(o[6],0.f), fmaxf(o[7],0.f));
      *(float4*)&hbuf[(long)wid*C + cg*8]     = r0;
      *(float4*)&hbuf[(long)wid*C + cg*8 + 4] = r1;
    }
    float f[8];
    #pragma unroll
    for (int i=0;i<8;++i) f[i] = o[i] + __shfl_xor(o[i], 8, 64);
    if (lane < 8){
      float4 f0 = make_float4(f[0],f[1],f[2],f[3]);
      float4 f1 = make_float4(f[4],f[5],f[6],f[7]);
      float4* fp = (float4*)&fin[(long)wid*64 + lane*8];
      if constexpr (LAYER==1){
        const float4* src; long off;
        if      (wid < I_N)      { src=(const float4*)embi; off=(long)wid*16; }
        else if (wid < I_N+U_N)  { src=(const float4*)embu; off=(long)(wid-I_N)*16; }
        else                     { src=(const float4*)embf; off=(long)(wid-I_N-U_N)*16; }
        float4 xa = src[off + lane*2], xb = src[off + lane*2 + 1];
        fp[0] = make_float4(xa.x+f0.x*0.5f, xa.y+f0.y*0.5f, xa.z+f0.z*0.5f, xa.w+f0.w*0.5f);
        fp[1] = make_float4(xb.x+f1.x*0.5f, xb.y+f1.y*0.5f, xb.z+f1.z*0.5f, xb.w+f1.w*0.5f);
      } else {
        float4 ca = fp[0], cb = fp[1];
        fp[0] = make_float4(ca.x+f0.x*0.5f, ca.y+f0.y*0.5f, ca.z+f0.z*0.5f, ca.w+f0.w*0.5f);
        fp[1] = make_float4(cb.x+f1.x*0.5f, cb.y+f1.y*0.5f, cb.z+f1.z*0.5f, cb.w+f1.w*0.5f);
      }
    }
  } else {
    if (lane < 8){
      const float4* fp = (const float4*)&fin[(long)wid*64 + lane*8];
      float4 ca = fp[0], cb = fp[1];
      float4 t0 = make_float4((ca.x+o[0])*0.25f,(ca.y+o[1])*0.25f,(ca.z+o[2])*0.25f,(ca.w+o[3])*0.25f);
      float4 t1 = make_float4((cb.x+o[4])*0.25f,(cb.y+o[5])*0.25f,(cb.z+o[6])*0.25f,(cb.w+o[7])*0.25f);
      ((float4*)outp)[(long)wid*16 + lane*2]            = t0;
      ((float4*)outp)[(long)wid*16 + lane*2 + 1]        = t1;
      ((float4*)outp)[(long)(NN+wid)*16 + lane*2]       = t0;
      ((float4*)outp)[(long)(NN+wid)*16 + lane*2 + 1]   = t1;
    }
  }

  if (segLen <= 64){
    if (lane < segLen){
      if constexpr (H==2)
        ((float2*)aout)[eid] = make_float2(p[0]*idv[0], p[1]*idv[1]);
      else
        aout[eid] = p[0]*idv[0];
    }
  } else {
    for (int base = n0; base < n1; base += 64){
      int cnt = n1 - base; if (cnt > 64) cnt = 64;
      if (lane < cnt){
        int ss = colsrc[base + lane];
        int ee = eids[base + lane];
        if constexpr (H==2){
          float2 a = ((const float2*)asrc)[ss];
          float w0 = __expf(leaky(a.x + ad[0]) - mx[0]) * idv[0];
          float w1 = __expf(leaky(a.y + ad[1]) - mx[1]) * idv[1];
          ((float2*)aout)[ee] = make_float2(w0, w1);
        } else {
          aout[ee] = __expf(leaky(asrc[ss] + ad[0]) - mx[0]) * idv[0];
        }
      }
    }
  }
}

extern "C" void kernel_launch(void* const* d_in, const int* in_sizes, int n_in,
                              void* d_out, int out_size, void* d_ws, size_t ws_size,
                              hipStream_t stream)
{
  (void)in_sizes; (void)n_in; (void)out_size; (void)ws_size;
  const int*   eidx  = (const int*)d_in[0];
  const int*   esrc  = eidx;
  const int*   edst  = eidx + EE;
  const float* emb_i = (const float*)d_in[1];
  const float* emb_u = (const float*)d_in[2];
  const float* emb_f = (const float*)d_in[3];
  const float* W1    = (const float*)d_in[4];
  const float* as1   = (const float*)d_in[5];
  const float* ad1   = (const float*)d_in[6];
  const float* b1    = (const float*)d_in[7];
  const float* W2    = (const float*)d_in[8];
  const float* as2   = (const float*)d_in[9];
  const float* ad2   = (const float*)d_in[10];
  const float* b2    = (const float*)d_in[11];
  const float* W3    = (const float*)d_in[12];
  const float* as3   = (const float*)d_in[13];
  const float* ad3   = (const float*)d_in[14];
  const float* b3    = (const float*)d_in[15];
  float* out = (float*)d_out;

  // workspace layout (256B aligned)
  char* p = (char*)d_ws;
  auto alloc = [&](size_t bytes)->char* {
    char* r = p; p += (bytes + 255) & ~(size_t)255; return r;
  };
  float*  fin  = (float*)alloc((size_t)NN*64*4);
  float*  hbuf = (float*)alloc((size_t)NN*128*4);
  __half* xwh  = (__half*)alloc((size_t)NN*128*2);
  float*  asrc = (float*)alloc((size_t)NN*2*4);
  float*  adst = (float*)alloc((size_t)NN*2*4);
  int* row_start = (int*)alloc((size_t)(NN+1)*4);
  int* colsrc    = (int*)alloc((size_t)ETOT*4);
  int* eids      = (int*)alloc((size_t)ETOT*4);
  unsigned long long* binned = (unsigned long long*)alloc((size_t)EE*8);
  int* bsize     = (int*)alloc((size_t)NBUCK*4);
  int* ebase     = (int*)alloc((size_t)NBUCK*4);
  int* rbase     = (int*)alloc((size_t)NBUCK*4);
  int* gcur      = (int*)alloc((size_t)NBUCK*4);
  __half* wt1    = (__half*)alloc((size_t)128*64*2);
  __half* wt2    = (__half*)alloc((size_t)128*128*2);
  __half* wt3    = (__half*)alloc((size_t)64*128*2);

  float* alpha1 = out + (size_t)12800000;
  float* alpha2 = out + (size_t)15400000;
  float* alpha3 = out + (size_t)18000000;

  // binned CSR build + weight transpose
  constexpr int NB_CHUNK = (EE + 4095)/4096;   // 293
  constexpr int NB_GEMM  = (NN + 63)/64;       // 1563
  zerob_k   <<<1, 256, 0, stream>>>(bsize);
  hist_k    <<<512, 256, 0, stream>>>(edst, bsize);
  bscan_k   <<<1, 256, 0, stream>>>(bsize, ebase, rbase, gcur, row_start);
  binplace_k<<<NB_CHUNK, 256, 0, stream>>>(esrc, edst, gcur, binned);
  wtrans_k  <<<64, 256, 0, stream>>>(W1, W2, W3, wt1, wt2, wt3);
  bbuild_k  <<<NBUCK, 512, 0, stream>>>(binned, bsize, ebase, rbase, row_start, colsrc, eids);

  // ---- Layer 1: K=64 -> C=128 (H=2), X = concat(embeddings) ----
  gemm_mfma_k<64,128,true><<<NB_GEMM,256,0,stream>>>(emb_i, emb_u, emb_f, wt1, as1, ad1, xwh, asrc, adst);
  aggregate_k<2,1><<<NN/4,256,0,stream>>>(xwh, asrc, adst, row_start, colsrc, eids, b1, alpha1,
                                          hbuf, fin, emb_i, emb_u, emb_f, nullptr);

  // ---- Layer 2: K=128 -> C=128 (H=2) ----
  gemm_mfma_k<128,128,false><<<NB_GEMM,256,0,stream>>>(hbuf, nullptr, nullptr, wt2, as2, ad2, xwh, asrc, adst);
  aggregate_k<2,2><<<NN/4,256,0,stream>>>(xwh, asrc, adst, row_start, colsrc, eids, b2, alpha2,
                                          hbuf, fin, nullptr, nullptr, nullptr, nullptr);

  // ---- Layer 3: K=128 -> C=64 (H=1), fused final write ----
  gemm_mfma_k<128,64,false><<<NB_GEMM,256,0,stream>>>(hbuf, nullptr, nullptr, wt3, as3, ad3, xwh, asrc, adst);
  aggregate_k<1,3><<<NN/4,256,0,stream>>>(xwh, asrc, adst, row_start, colsrc, eids, b3, alpha3,
                                          nullptr, fin, nullptr, nullptr, nullptr, out);
}

// Round 9
// 461.378 us; speedup vs baseline: 1.0399x; 1.0399x over previous
//
#include <hip/hip_runtime.h>
#include <hip/hip_fp16.h>
#include <math.h>

// Problem constants (fixed by reference)
constexpr int I_N = 40000, U_N = 30000, F_N = 30000;
constexpr int NN   = 100000;           // total nodes
constexpr int EE   = 1200000;          // edges (without self loops)
constexpr int ETOT = EE + NN;          // edges + self loops
constexpr int NBUCK = (NN + 511)/512;  // 196 dst-buckets of 512 nodes

using half8   = __attribute__((ext_vector_type(8))) _Float16;
using h2v     = __attribute__((ext_vector_type(2))) _Float16;
using floatx4 = __attribute__((ext_vector_type(4))) float;

__device__ __forceinline__ float leaky(float x){ return x > 0.f ? x : 0.2f*x; }

// ---------------- binned CSR build ----------------
__global__ __launch_bounds__(256) void hist_k(const int* __restrict__ edst, int* __restrict__ bsize){
  __shared__ int h[NBUCK];
  for (int i = threadIdx.x; i < NBUCK; i += 256) h[i] = 0;
  __syncthreads();
  int stride = gridDim.x*256;
  for (int e = blockIdx.x*256 + threadIdx.x; e < EE; e += stride)
    atomicAdd(&h[edst[e] >> 9], 1);
  __syncthreads();
  for (int i = threadIdx.x; i < NBUCK; i += 256)
    if (h[i]) atomicAdd(&bsize[i], h[i]);
}

__global__ __launch_bounds__(256) void bscan_k(const int* __restrict__ bsize,
                                               int* __restrict__ ebase, int* __restrict__ rbase,
                                               int* __restrict__ gcur, int* __restrict__ row_start){
  __shared__ int sb[NBUCK], se[NBUCK], sr[NBUCK];
  int t = threadIdx.x;
  for (int i = t; i < NBUCK; i += 256) sb[i] = bsize[i];
  __syncthreads();
  if (t == 0){
    int e = 0, r = 0;
    for (int b = 0; b < NBUCK; ++b){
      int nloc = NN - b*512; if (nloc > 512) nloc = 512;
      se[b] = e; sr[b] = r;
      e += sb[b]; r += sb[b] + nloc;
    }
    row_start[NN] = ETOT;
  }
  __syncthreads();
  for (int i = t; i < NBUCK; i += 256){
    ebase[i] = se[i]; gcur[i] = se[i]; rbase[i] = sr[i];
  }
}

// place edges into bucket-contiguous binned[]; no big LDS stage (re-read from L2)
__global__ __launch_bounds__(256) void binplace_k(const int* __restrict__ esrc,
                                                  const int* __restrict__ edst,
                                                  int* __restrict__ gcur,
                                                  unsigned long long* __restrict__ binned){
  constexpr int CHUNK = 2048;
  __shared__ int h[NBUCK], bb[NBUCK], cur[NBUCK];
  int e0 = blockIdx.x*CHUNK;
  int n = EE - e0; if (n > CHUNK) n = CHUNK;
  for (int i = threadIdx.x; i < NBUCK; i += 256){ h[i] = 0; cur[i] = 0; }
  __syncthreads();
  for (int i = threadIdx.x; i < n; i += 256)
    atomicAdd(&h[edst[e0+i] >> 9], 1);
  __syncthreads();
  for (int b = threadIdx.x; b < NBUCK; b += 256)
    bb[b] = h[b] ? atomicAdd(&gcur[b], h[b]) : 0;
  __syncthreads();
  for (int i = threadIdx.x; i < n; i += 256){
    int s = esrc[e0+i], d = edst[e0+i], b = d >> 9;
    int p = bb[b] + atomicAdd(&cur[b], 1);
    binned[p] = ((unsigned long long)(unsigned)(e0+i) << 32)
              | (unsigned)(s | ((d & 511) << 17));
  }
}

// per bucket: LDS counts, scan, CSR segment build -> packed (src,eid) per slot
__global__ __launch_bounds__(512) void bbuild_k(const unsigned long long* __restrict__ binned,
                                                const int* __restrict__ bsize,
                                                const int* __restrict__ ebase, const int* __restrict__ rbase,
                                                int* __restrict__ row_start,
                                                int2* __restrict__ colse){
  __shared__ int sm[512], curs[512];
  int b = blockIdx.x, t = threadIdx.x;
  int nbase = b*512;
  int NLOC = NN - nbase; if (NLOC > 512) NLOC = 512;
  int sz = bsize[b], eb = ebase[b], rb = rbase[b];
  sm[t] = (t < NLOC) ? 1 : 0;                  // self loop
  __syncthreads();
  for (int i = t; i < sz; i += 512){
    int lo = (int)(binned[eb+i] & 0xFFFFFFFFu);
    atomicAdd(&sm[(lo >> 17) & 511], 1);
  }
  __syncthreads();
  int myc = sm[t];
  for (int off = 1; off < 512; off <<= 1){
    int x = (t >= off) ? sm[t-off] : 0;
    __syncthreads();
    sm[t] += x;
    __syncthreads();
  }
  int excl = sm[t] - myc;
  if (t < NLOC){
    row_start[nbase+t] = rb + excl;
    colse[rb+excl] = make_int2(nbase + t, EE + nbase + t);   // self loop first
  }
  curs[t] = excl + ((t < NLOC) ? 1 : 0);
  __syncthreads();
  for (int i = t; i < sz; i += 512){
    unsigned long long v = binned[eb+i];
    int lo  = (int)(v & 0xFFFFFFFFu);
    int dl  = (lo >> 17) & 511;
    int src = lo & 0x1FFFF;
    int p = rb + atomicAdd(&curs[dl], 1);
    colse[p] = make_int2(src, (int)(v >> 32));
  }
}

// ---------------- one-time weight transpose W(KxC) -> WT(CxK) fp16 ----------------
__global__ __launch_bounds__(256) void wtrans_k(const float* __restrict__ W1,
                                                const float* __restrict__ W2,
                                                const float* __restrict__ W3,
                                                __half* __restrict__ wt1,
                                                __half* __restrict__ wt2,
                                                __half* __restrict__ wt3){
  int i = blockIdx.x*256 + threadIdx.x;
  if (i < 64*128){  int k = i >> 7, c = i & 127; wt1[c*64  + k] = __float2half(W1[i]); }
  if (i < 128*128){ int k = i >> 7, c = i & 127; wt2[c*128 + k] = __float2half(W2[i]); }
  if (i < 128*64){  int k = i >> 6, c = i & 63;  wt3[c*128 + k] = __float2half(W3[i]); }
}

// ---------------- MFMA GEMM (+ fused attention dots) ----------------
// CONCAT: X = fp32 concat(embeddings). Else: X = fp16 hbuf (straight copy).
template<int K, int C, bool CONCAT>
__global__ __launch_bounds__(256) void gemm_mfma_k(
    const float* __restrict__ Xa, const float* __restrict__ Xb, const float* __restrict__ Xc,
    const __half* __restrict__ XH,
    const __half* __restrict__ WT,
    const float* __restrict__ atts, const float* __restrict__ attd,
    __half* __restrict__ XWH, float* __restrict__ asrc, float* __restrict__ adst)
{
  constexpr int RPB = 64;
  constexpr int H   = C/64;
  constexpr int NCT = C/16;
  constexpr size_t STAGE_B = (size_t)(RPB*K + C*K)*2;
  constexpr size_t EPI_B   = (size_t)RPB*(C+4)*4;
  constexpr size_t SMEM_B  = STAGE_B > EPI_B ? STAGE_B : EPI_B;
  __shared__ __align__(16) char smem[SMEM_B];
  _Float16* Xs = (_Float16*)smem;          // [RPB][K]
  _Float16* Bs = Xs + RPB*K;               // [C][K]
  float*    Es = (float*)smem;             // [RPB][C+4] epilogue

  int t = threadIdx.x;
  long rbase = (long)blockIdx.x * RPB;

  if constexpr (CONCAT){
    for (int i = t; i < RPB*K/4; i += 256){
      float4 v = make_float4(0.f,0.f,0.f,0.f);
      long gi = rbase*(K/4) + i;
      if      (gi < (long)I_N*(K/4))        v = ((const float4*)Xa)[gi];
      else if (gi < (long)(I_N+U_N)*(K/4))  v = ((const float4*)Xb)[gi - (long)I_N*(K/4)];
      else if (gi < (long)NN*(K/4))         v = ((const float4*)Xc)[gi - (long)(I_N+U_N)*(K/4)];
      union { __half2 h2[2]; uint2 u; } pk;
      pk.h2[0] = __floats2half2_rn(v.x, v.y);
      pk.h2[1] = __floats2half2_rn(v.z, v.w);
      ((uint2*)Xs)[i] = pk.u;
    }
  } else {
    for (int i = t; i < RPB*K/8; i += 256){
      int row = i/(K/8);
      uint4 v = make_uint4(0,0,0,0);
      if (rbase + row < NN) v = ((const uint4*)(XH + rbase*K))[i];
      ((uint4*)Xs)[i] = v;
    }
  }
  for (int i = t; i < C*K/8; i += 256)
    ((uint4*)Bs)[i] = ((const uint4*)WT)[i];
  __syncthreads();

  const int wid = t >> 6, lane = t & 63;
  const int l15 = lane & 15, lk = lane >> 4;
  floatx4 acc[NCT];
  #pragma unroll
  for (int i = 0; i < NCT; ++i) acc[i] = (floatx4){0.f,0.f,0.f,0.f};

  const _Float16* arow = Xs + (wid*16 + l15)*K + lk*8;
  const _Float16* brow = Bs + l15*K + lk*8;
  #pragma unroll
  for (int ks = 0; ks < K/32; ++ks){
    half8 a = *(const half8*)(arow + ks*32);
    #pragma unroll
    for (int ct = 0; ct < NCT; ++ct){
      half8 b = *(const half8*)(brow + ct*16*K + ks*32);
      acc[ct] = __builtin_amdgcn_mfma_f32_16x16x32_f16(a, b, acc[ct], 0, 0, 0);
    }
  }

  float asv[NCT], adv[NCT];
  #pragma unroll
  for (int ct = 0; ct < NCT; ++ct){
    asv[ct] = atts[ct*16 + l15];
    adv[ct] = attd[ct*16 + l15];
  }
  #pragma unroll
  for (int reg = 0; reg < 4; ++reg){
    float p0s = 0.f, p0d = 0.f, p1s = 0.f, p1d = 0.f;
    #pragma unroll
    for (int ct = 0; ct < NCT; ++ct){
      float v = acc[ct][reg];
      if (H == 2 && ct >= NCT/2){ p1s = fmaf(v, asv[ct], p1s); p1d = fmaf(v, adv[ct], p1d); }
      else                      { p0s = fmaf(v, asv[ct], p0s); p0d = fmaf(v, adv[ct], p0d); }
    }
    #pragma unroll
    for (int m = 1; m < 16; m <<= 1){
      p0s += __shfl_xor(p0s, m, 64); p0d += __shfl_xor(p0d, m, 64);
      if (H == 2){ p1s += __shfl_xor(p1s, m, 64); p1d += __shfl_xor(p1d, m, 64); }
    }
    if (l15 == 0){
      long r = rbase + wid*16 + lk*4 + reg;
      if (r < NN){
        asrc[r*H] = p0s; adst[r*H] = p0d;
        if (H == 2){ asrc[r*H+1] = p1s; adst[r*H+1] = p1d; }
      }
    }
  }

  __syncthreads();
  #pragma unroll
  for (int ct = 0; ct < NCT; ++ct)
    #pragma unroll
    for (int reg = 0; reg < 4; ++reg)
      Es[(wid*16 + lk*4 + reg)*(C+4) + ct*16 + l15] = acc[ct][reg];
  __syncthreads();
  for (int i = t; i < RPB*C/4; i += 256){
    int row = i/(C/4), c4 = (i%(C/4))*4;
    if (rbase + row >= NN) continue;
    float4 v = *(const float4*)&Es[row*(C+4) + c4];
    union { __half2 h2[2]; uint2 u; } pk;
    pk.h2[0] = __floats2half2_rn(v.x, v.y);
    pk.h2[1] = __floats2half2_rn(v.z, v.w);
    *(uint2*)&XWH[(rbase+row)*C + c4] = pk.u;
  }
}

// ---------------- aggregation: online softmax + pk_fma_f16 gather + fused alpha/final --
template<int H, int LAYER>
__global__ __launch_bounds__(256) void aggregate_k(
    const __half* __restrict__ XWH, const float* __restrict__ asrc, const float* __restrict__ adst,
    const int* __restrict__ row_start, const int2* __restrict__ colse,
    const float* __restrict__ bias, float* __restrict__ aout,
    __half* __restrict__ hbufH, float* __restrict__ fin,
    const float* __restrict__ embi, const float* __restrict__ embu, const float* __restrict__ embf,
    float* __restrict__ outp)
{
  constexpr int C = H*64;
  constexpr unsigned ROWB = C*2;               // row bytes (fp16)
  int widx = threadIdx.x >> 6;                 // wave within block
  int wid  = (blockIdx.x*256 + threadIdx.x) >> 6;
  int lane = threadIdx.x & 63;
  __shared__ unsigned ldsOff[4][64];
  __shared__ unsigned ldsQ[4][H][64];
  if (wid >= NN) return;
  int n0 = row_start[wid], n1 = row_start[wid+1];
  int segLen = n1 - n0;

  float ad[H];
  if constexpr (H==2){ float2 t = ((const float2*)adst)[wid]; ad[0]=t.x; ad[1]=t.y; }
  else                 ad[0] = adst[wid];

  constexpr int SL_SH = (H==2) ? 4 : 3;
  const int slot = lane >> SL_SH;
  const int cg   = lane & ((1<<SL_SH)-1);
  const int hd   = (H==2) ? (cg>>3) : 0;
  const char* xwb = (const char*)XWH;
  const unsigned cgoff = (unsigned)cg*16;

  float mx[H], den[H];
  #pragma unroll
  for (int h=0; h<H; ++h){ mx[h] = -3.402823466e38f; den[h] = 0.f; }
  h2v acch[4];
  #pragma unroll
  for (int i=0;i<4;++i) acch[i] = (h2v){(_Float16)0.f, (_Float16)0.f};

  int s = 0, eid = 0;
  float p[H];
  #pragma unroll
  for (int h=0; h<H; ++h) p[h] = 0.f;

  for (int base = n0; base < n1; base += 64){
    int cnt = n1 - base; if (cnt > 64) cnt = 64;
    float e[H];
    #pragma unroll
    for (int h=0; h<H; ++h) e[h] = -3.402823466e38f;
    if (lane < cnt){
      int2 se = colse[base + lane];
      s = se.x; eid = se.y;
      if constexpr (H==2){
        float2 a = ((const float2*)asrc)[s];
        e[0] = leaky(a.x + ad[0]); e[1] = leaky(a.y + ad[1]);
      } else {
        e[0] = leaky(asrc[s] + ad[0]);
      }
    }
    float sc[H];
    #pragma unroll
    for (int h=0; h<H; ++h){
      float bm = e[h];
      #pragma unroll
      for (int m=1; m<64; m<<=1) bm = fmaxf(bm, __shfl_xor(bm, m, 64));
      float nm = fmaxf(mx[h], bm);
      p[h] = (lane < cnt) ? __expf(e[h] - nm) : 0.f;
      if (base == n0){
        den[h] = p[h]; sc[h] = 1.f;
      } else {
        sc[h] = __expf(mx[h] - nm);
        den[h] = den[h]*sc[h] + p[h];
      }
      mx[h] = nm;
    }
    if (base != n0){
      float asc = (H==2) ? sc[hd] : sc[0];
      h2v av = {(_Float16)asc, (_Float16)asc};
      #pragma unroll
      for (int i=0;i<4;++i) acch[i] *= av;
    }

    // stage gather operands in wave-private LDS
    ldsOff[widx][lane] = (lane < cnt) ? (unsigned)s * ROWB : 0u;
    #pragma unroll
    for (int h=0; h<H; ++h){
      union { __half2 h2; unsigned u; } qq;
      qq.h2 = __floats2half2_rn(p[h], p[h]);
      ldsQ[widx][h][lane] = qq.u;
    }
    __builtin_amdgcn_wave_barrier();

    constexpr int EPI = 64 >> SL_SH;
    for (int j = 0; j < cnt; j += 2*EPI){
      unsigned off[2], qpk[2];
      #pragma unroll
      for (int u=0; u<2; ++u){
        int ei = j + u*EPI + slot;
        off[u] = ldsOff[widx][ei];
        qpk[u] = ldsQ[widx][hd][ei];
      }
      #pragma unroll
      for (int u=0; u<2; ++u){
        float4 raw = *(const float4*)(xwb + (off[u] + cgoff));
        union { float4 f; h2v h[4]; } cv; cv.f = raw;
        union { unsigned u; h2v h; } qv; qv.u = qpk[u];
        #pragma unroll
        for (int i=0;i<4;++i)
          acch[i] = __builtin_elementwise_fma(qv.h, cv.h[i], acch[i]);
      }
    }
    __builtin_amdgcn_wave_barrier();
  }

  float idv[H];
  #pragma unroll
  for (int h=0; h<H; ++h){
    #pragma unroll
    for (int m=1; m<64; m<<=1) den[h] += __shfl_xor(den[h], m, 64);
    idv[h] = 1.0f/(den[h] + 1e-16f);
  }

  float accv[8];
  #pragma unroll
  for (int i=0;i<4;++i){ accv[2*i] = (float)acch[i][0]; accv[2*i+1] = (float)acch[i][1]; }

  // combine edge-slot partial sums: lanes with same cg
  #pragma unroll
  for (int i=0;i<8;++i){
    if constexpr (H==1) accv[i] += __shfl_xor(accv[i], 8, 64);
    accv[i] += __shfl_xor(accv[i], 16, 64);
    accv[i] += __shfl_xor(accv[i], 32, 64);
  }

  float myId = (H==2) ? idv[hd] : idv[0];
  float4 b0 = *(const float4*)&bias[cg*8];
  float4 b1 = *(const float4*)&bias[cg*8 + 4];
  float o[8];
  o[0]=accv[0]*myId+b0.x; o[1]=accv[1]*myId+b0.y; o[2]=accv[2]*myId+b0.z; o[3]=accv[3]*myId+b0.w;
  o[4]=accv[4]*myId+b1.x; o[5]=accv[5]*myId+b1.y; o[6]=accv[6]*myId+b1.z; o[7]=accv[7]*myId+b1.w;

  if constexpr (LAYER==1 || LAYER==2){
    if (lane < 16){
      union { __half2 h2[4]; uint4 u; } r;
      r.h2[0] = __floats2half2_rn(fmaxf(o[0],0.f), fmaxf(o[1],0.f));
      r.h2[1] = __floats2half2_rn(fmaxf(o[2],0.f), fmaxf(o[3],0.f));
      r.h2[2] = __floats2half2_rn(fmaxf(o[4],0.f), fmaxf(o[5],0.f));
      r.h2[3] = __floats2half2_rn(fmaxf(o[6],0.f), fmaxf(o[7],0.f));
      *(uint4*)&hbufH[(long)wid*C + cg*8] = r.u;
    }
    float f[8];
    #pragma unroll
    for (int i=0;i<8;++i) f[i] = o[i] + __shfl_xor(o[i], 8, 64);
    if (lane < 8){
      float4 f0 = make_float4(f[0],f[1],f[2],f[3]);
      float4 f1 = make_float4(f[4],f[5],f[6],f[7]);
      float4* fp = (float4*)&fin[(long)wid*64 + lane*8];
      if constexpr (LAYER==1){
        const float4* src; long off;
        if      (wid < I_N)      { src=(const float4*)embi; off=(long)wid*16; }
        else if (wid < I_N+U_N)  { src=(const float4*)embu; off=(long)(wid-I_N)*16; }
        else                     { src=(const float4*)embf; off=(long)(wid-I_N-U_N)*16; }
        float4 xa = src[off + lane*2], xb = src[off + lane*2 + 1];
        fp[0] = make_float4(xa.x+f0.x*0.5f, xa.y+f0.y*0.5f, xa.z+f0.z*0.5f, xa.w+f0.w*0.5f);
        fp[1] = make_float4(xb.x+f1.x*0.5f, xb.y+f1.y*0.5f, xb.z+f1.z*0.5f, xb.w+f1.w*0.5f);
      } else {
        float4 ca = fp[0], cb = fp[1];
        fp[0] = make_float4(ca.x+f0.x*0.5f, ca.y+f0.y*0.5f, ca.z+f0.z*0.5f, ca.w+f0.w*0.5f);
        fp[1] = make_float4(cb.x+f1.x*0.5f, cb.y+f1.y*0.5f, cb.z+f1.z*0.5f, cb.w+f1.w*0.5f);
      }
    }
  } else {
    if (lane < 8){
      const float4* fp = (const float4*)&fin[(long)wid*64 + lane*8];
      float4 ca = fp[0], cb = fp[1];
      float4 t0 = make_float4((ca.x+o[0])*0.25f,(ca.y+o[1])*0.25f,(ca.z+o[2])*0.25f,(ca.w+o[3])*0.25f);
      float4 t1 = make_float4((cb.x+o[4])*0.25f,(cb.y+o[5])*0.25f,(cb.z+o[6])*0.25f,(cb.w+o[7])*0.25f);
      ((float4*)outp)[(long)wid*16 + lane*2]            = t0;
      ((float4*)outp)[(long)wid*16 + lane*2 + 1]        = t1;
      ((float4*)outp)[(long)(NN+wid)*16 + lane*2]       = t0;
      ((float4*)outp)[(long)(NN+wid)*16 + lane*2 + 1]   = t1;
    }
  }

  if (segLen <= 64){
    if (lane < segLen){
      if constexpr (H==2)
        ((float2*)aout)[eid] = make_float2(p[0]*idv[0], p[1]*idv[1]);
      else
        aout[eid] = p[0]*idv[0];
    }
  } else {
    for (int base = n0; base < n1; base += 64){
      int cnt = n1 - base; if (cnt > 64) cnt = 64;
      if (lane < cnt){
        int2 se = colse[base + lane];
        if constexpr (H==2){
          float2 a = ((const float2*)asrc)[se.x];
          float w0 = __expf(leaky(a.x + ad[0]) - mx[0]) * idv[0];
          float w1 = __expf(leaky(a.y + ad[1]) - mx[1]) * idv[1];
          ((float2*)aout)[se.y] = make_float2(w0, w1);
        } else {
          aout[se.y] = __expf(leaky(asrc[se.x] + ad[0]) - mx[0]) * idv[0];
        }
      }
    }
  }
}

extern "C" void kernel_launch(void* const* d_in, const int* in_sizes, int n_in,
                              void* d_out, int out_size, void* d_ws, size_t ws_size,
                              hipStream_t stream)
{
  (void)in_sizes; (void)n_in; (void)out_size; (void)ws_size;
  const int*   eidx  = (const int*)d_in[0];
  const int*   esrc  = eidx;
  const int*   edst  = eidx + EE;
  const float* emb_i = (const float*)d_in[1];
  const float* emb_u = (const float*)d_in[2];
  const float* emb_f = (const float*)d_in[3];
  const float* W1    = (const float*)d_in[4];
  const float* as1   = (const float*)d_in[5];
  const float* ad1   = (const float*)d_in[6];
  const float* b1    = (const float*)d_in[7];
  const float* W2    = (const float*)d_in[8];
  const float* as2   = (const float*)d_in[9];
  const float* ad2   = (const float*)d_in[10];
  const float* b2    = (const float*)d_in[11];
  const float* W3    = (const float*)d_in[12];
  const float* as3   = (const float*)d_in[13];
  const float* ad3   = (const float*)d_in[14];
  const float* b3    = (const float*)d_in[15];
  float* out = (float*)d_out;

  // workspace layout (256B aligned)
  char* p = (char*)d_ws;
  auto alloc = [&](size_t bytes)->char* {
    char* r = p; p += (bytes + 255) & ~(size_t)255; return r;
  };
  float*  fin   = (float*)alloc((size_t)NN*64*4);
  __half* hbufH = (__half*)alloc((size_t)NN*128*2);
  __half* xwh   = (__half*)alloc((size_t)NN*128*2);
  float*  asrc  = (float*)alloc((size_t)NN*2*4);
  float*  adst  = (float*)alloc((size_t)NN*2*4);
  int*  row_start = (int*)alloc((size_t)(NN+1)*4);
  int2* colse     = (int2*)alloc((size_t)ETOT*8);
  unsigned long long* binned = (unsigned long long*)alloc((size_t)EE*8);
  int* bsize     = (int*)alloc((size_t)NBUCK*4);
  int* ebase     = (int*)alloc((size_t)NBUCK*4);
  int* rbase     = (int*)alloc((size_t)NBUCK*4);
  int* gcur      = (int*)alloc((size_t)NBUCK*4);
  __half* wt1    = (__half*)alloc((size_t)128*64*2);
  __half* wt2    = (__half*)alloc((size_t)128*128*2);
  __half* wt3    = (__half*)alloc((size_t)64*128*2);

  float* alpha1 = out + (size_t)12800000;
  float* alpha2 = out + (size_t)15400000;
  float* alpha3 = out + (size_t)18000000;

  // binned CSR build + weight transpose
  constexpr int NB_CHUNK = (EE + 2047)/2048;   // 586
  constexpr int NB_GEMM  = (NN + 63)/64;       // 1563
  hipMemsetAsync(bsize, 0, (size_t)NBUCK*4, stream);
  hist_k    <<<512, 256, 0, stream>>>(edst, bsize);
  bscan_k   <<<1, 256, 0, stream>>>(bsize, ebase, rbase, gcur, row_start);
  binplace_k<<<NB_CHUNK, 256, 0, stream>>>(esrc, edst, gcur, binned);
  wtrans_k  <<<64, 256, 0, stream>>>(W1, W2, W3, wt1, wt2, wt3);
  bbuild_k  <<<NBUCK, 512, 0, stream>>>(binned, bsize, ebase, rbase, row_start, colse);

  // ---- Layer 1: K=64 -> C=128 (H=2), X = concat(embeddings) ----
  gemm_mfma_k<64,128,true><<<NB_GEMM,256,0,stream>>>(emb_i, emb_u, emb_f, nullptr, wt1, as1, ad1, xwh, asrc, adst);
  aggregate_k<2,1><<<NN/4,256,0,stream>>>(xwh, asrc, adst, row_start, colse, b1, alpha1,
                                          hbufH, fin, emb_i, emb_u, emb_f, nullptr);

  // ---- Layer 2: K=128 -> C=128 (H=2) ----
  gemm_mfma_k<128,128,false><<<NB_GEMM,256,0,stream>>>(nullptr, nullptr, nullptr, hbufH, wt2, as2, ad2, xwh, asrc, adst);
  aggregate_k<2,2><<<NN/4,256,0,stream>>>(xwh, asrc, adst, row_start, colse, b2, alpha2,
                                          hbufH, fin, nullptr, nullptr, nullptr, nullptr);

  // ---- Layer 3: K=128 -> C=64 (H=1), fused final write ----
  gemm_mfma_k<128,64,false><<<NB_GEMM,256,0,stream>>>(nullptr, nullptr, nullptr, hbufH, wt3, as3, ad3, xwh, asrc, adst);
  aggregate_k<1,3><<<NN/4,256,0,stream>>>(xwh, asrc, adst, row_start, colse, b3, alpha3,
                                          nullptr, fin, nullptr, nullptr, nullptr, out);
}